// Round 11
// baseline (843.869 us; speedup 1.0000x reference)
//
#include <hip/hip_runtime.h>
#include <hip/hip_bf16.h>
#include <hip/hip_fp16.h>
#include <math.h>

// Problem dims (fixed by reference)
#define B_  32
#define T_  512
#define F_  4096
#define H_  128
#define G4H 512           // 4*H
#define NCLS 3            // NUM_CLASSES + 1
#define M_  (B_ * T_)     // 16384 rows
#define KSTEPS 128        // F_/32

typedef _Float16 f16x8 __attribute__((ext_vector_type(8)));
typedef _Float16 f16x4 __attribute__((ext_vector_type(4)));
typedef float    f32x4 __attribute__((ext_vector_type(4)));

// ---------------------------------------------------------------------------
// Kernel 0b: Wk [F,4H] fp32 -> btK fp16, K-MAJOR tiles with baked-in group
// swizzle: group g (8 halves) of column n stored at half-offset
//   n*32 + ((g ^ ((n>>1)&3)) << 3)
// ---------------------------------------------------------------------------
__global__ __launch_bounds__(256) void cvt_wkT(
    const float* __restrict__ Wk, _Float16* __restrict__ btK)
{
    __shared__ float ls[64][65];
    const int k0 = blockIdx.x * 64;
    const int n0 = blockIdx.y * 64;
    const int tid = threadIdx.x;

    {
        int r  = tid >> 4;
        int c4 = (tid & 15) * 4;
        #pragma unroll
        for (int p = 0; p < 4; ++p) {
            float4 v = *reinterpret_cast<const float4*>(
                &Wk[(size_t)(k0 + r + p * 16) * G4H + n0 + c4]);
            ls[r + p * 16][c4 + 0] = v.x;
            ls[r + p * 16][c4 + 1] = v.y;
            ls[r + p * 16][c4 + 2] = v.z;
            ls[r + p * 16][c4 + 3] = v.w;
        }
    }
    __syncthreads();
    {
        int rn = tid >> 2;            // n within tile 0..63
        int ck = (tid & 3) * 16;      // k within tile 0,16,32,48
        f16x8 h0, h1;
        #pragma unroll
        for (int j = 0; j < 8; ++j) {
            h0[j] = (_Float16)ls[ck + j][rn];
            h1[j] = (_Float16)ls[ck + 8 + j][rn];
        }
        const int n    = n0 + rn;
        const int kg   = k0 + ck;
        const int kblk = kg >> 5;
        const int kk   = kg & 31;           // 0 or 16
        const int g0   = kk >> 3;           // 0 or 2
        const int sw   = (n >> 1) & 3;
        _Float16* base = btK + (size_t)kblk * (512 * 32) + (size_t)n * 32;
        *reinterpret_cast<f16x8*>(base + ((g0 ^ sw) << 3))       = h0;
        *reinterpret_cast<f16x8*>(base + (((g0 + 1) ^ sw) << 3)) = h1;
    }
}

// ---------------------------------------------------------------------------
// Kernel 0c: Wr transpose + zero the 128 producer flags (block (0,0)).
// ---------------------------------------------------------------------------
__global__ __launch_bounds__(256) void cvt_wrT(
    const float* __restrict__ Wr, _Float16* __restrict__ wrT,
    unsigned int* __restrict__ flags)
{
    __shared__ float ls[64][65];
    const int k0 = blockIdx.x * 64;
    const int n0 = blockIdx.y * 64;
    const int tid = threadIdx.x;
    if (blockIdx.x == 0 && blockIdx.y == 0 && tid < 128) flags[tid] = 0u;
    {
        int r  = tid >> 4;
        int c4 = (tid & 15) * 4;
        #pragma unroll
        for (int p = 0; p < 4; ++p) {
            float4 v = *reinterpret_cast<const float4*>(
                &Wr[(size_t)(k0 + r + p * 16) * G4H + n0 + c4]);
            ls[r + p * 16][c4 + 0] = v.x;
            ls[r + p * 16][c4 + 1] = v.y;
            ls[r + p * 16][c4 + 2] = v.z;
            ls[r + p * 16][c4 + 3] = v.w;
        }
    }
    __syncthreads();
    {
        int rn = tid >> 2;
        int ck = (tid & 3) * 16;
        f16x8 h0, h1;
        #pragma unroll
        for (int j = 0; j < 8; ++j) {
            h0[j] = (_Float16)ls[ck + j][rn];
            h1[j] = (_Float16)ls[ck + 8 + j][rn];
        }
        _Float16* dst = &wrT[(size_t)(n0 + rn) * H_ + k0 + ck];
        *reinterpret_cast<f16x8*>(dst)     = h0;
        *reinterpret_cast<f16x8*>(dst + 8) = h1;
    }
}

// Light producer-consumer barrier: LDS-drain only, no vmcnt drain.
__device__ __forceinline__ void lds_barrier() {
    asm volatile("s_waitcnt lgkmcnt(0)" ::: "memory");
    __builtin_amdgcn_s_barrier();
    asm volatile("" ::: "memory");
}

__device__ __forceinline__ float tanh_f(float x) {
    return 1.0f - 2.0f * __builtin_amdgcn_rcpf(
        1.0f + __builtin_amdgcn_exp2f(2.885390081777927f * x));
}
__device__ __forceinline__ float sig_f(float x) {
    return __builtin_amdgcn_rcpf(
        1.0f + __builtin_amdgcn_exp2f(-1.442695040888963f * x));
}

__device__ __forceinline__ void wait4(unsigned int* f) {
    while (__hip_atomic_load(f, __ATOMIC_ACQUIRE, __HIP_MEMORY_SCOPE_AGENT) < 4u)
        __builtin_amdgcn_s_sleep(2);
}

// ===========================================================================
// OVERLAP PATH: one 256-block x 1024-thread kernel.
//   bid 0..31   : LSTM consumer (1 batch each, EXCLUSIVE CU via vgpr>64)
//   bid 32..255 : GEMM producer (224 blocks, 16 waves = 2 x R23 sub-blocks)
// Work item = 128 rows (one batch-slice) x 256 cols x 64 K-steps (split-K/2).
// 512 items, slice-major, strided by 224 -> slice flags at ~77/155/155/232us.
// z produced as two f32 partials zA (kh=0) / zB (kh=1, +bias); lstm adds.
// ===========================================================================
__global__ __launch_bounds__(1024) void fused_overlap(
    const float* __restrict__ x, const _Float16* __restrict__ btK,
    const float* __restrict__ bias, float* __restrict__ zA,
    float* __restrict__ zB, const _Float16* __restrict__ wrT,
    float* __restrict__ hs, unsigned int* __restrict__ flags)
{
    // 32 pad VGPRs (opaque asm init, consumed at end) -> vgpr_count > 64
    // -> 8 waves/SIMD impossible -> exactly ONE block per CU. [R19 fix (b)]
    float pv[32];
    #pragma unroll
    for (int i = 0; i < 32; ++i)
        asm volatile("v_mov_b32 %0, %1" : "=v"(pv[i]) : "v"((float)i));

    __shared__ __align__(16) char smem[65536];
    const int tid = threadIdx.x;
    const int bid = blockIdx.x;

    if (bid >= 32) {
        // ------------------------- GEMM producer -------------------------
        const int lt = tid & 511;          // sub-block-local thread
        const int vb = tid >> 9;           // sub-block 0/1 (m-halves)
        const int w  = lt >> 6;
        const int l  = lt & 63;
        const int fr = l & 15;
        const int q  = l >> 4;

        const int ar = lt >> 3;
        const int hc = (lt & 7) * 4;
        const int abyte = ((((hc >> 3) ^ ((ar >> 1) & 3)) << 4) | ((hc << 1) & 15));

        char* AsB = smem + vb * 32768;     // [G][s] 4KB slots, 32KB/sub-block

        for (int it = bid - 32; it < 512; it += 224) {
            const int s  = it >> 7;        // t-slice 0..3
            const int r  = it & 127;
            const int b  = r >> 2;         // batch
            const int nh = (r >> 1) & 1;   // n-half
            const int kh = r & 1;          // K-half
            const int m0 = b * T_ + s * 128 + vb * 64;
            const int n0 = nh * 256;
            const int kb = kh * 64;

            const float* xrow = x + (size_t)(m0 + ar) * F_ + hc;
            const int nA = n0 + w * 32 + fr;
            const int nB = nA + 16;
            const _Float16* bp0 = btK + (size_t)nA * 32 + ((q ^ ((nA >> 1) & 3)) << 3);
            const _Float16* bp1 = btK + (size_t)nB * 32 + ((q ^ ((nB >> 1) & 3)) << 3);

            #define LOADB(t, bfv)                                             \
            {                                                                 \
                bfv[0] = *reinterpret_cast<const f16x8*>(bp0 + (size_t)(t) * 16384); \
                bfv[1] = *reinterpret_cast<const f16x8*>(bp1 + (size_t)(t) * 16384); \
            }
            #define LOADX(t) (*reinterpret_cast<const float4*>(xrow + (size_t)(t) * 32))
            #define WRITE_A(v, G, ss)                                         \
            {                                                                 \
                f16x4 hh; hh[0] = (_Float16)v.x; hh[1] = (_Float16)v.y;       \
                hh[2] = (_Float16)v.z; hh[3] = (_Float16)v.w;                 \
                *reinterpret_cast<f16x4*>(                                    \
                    AsB + ((G) * 4 + (ss)) * 4096 + ar * 64 + abyte) = hh;    \
            }
            #define COMPUTE(G, ss, bfv)                                       \
            {                                                                 \
                f16x8 af[4];                                                  \
                _Pragma("unroll")                                             \
                for (int i = 0; i < 4; ++i) {                                 \
                    int rr  = i * 16 + fr;                                    \
                    int off = rr * 64 + ((q ^ ((rr >> 1) & 3)) << 4);         \
                    af[i] = *reinterpret_cast<const f16x8*>(                  \
                        AsB + ((G) * 4 + (ss)) * 4096 + off);                 \
                }                                                             \
                _Pragma("unroll")                                             \
                for (int i = 0; i < 4; ++i)                                   \
                    _Pragma("unroll")                                         \
                    for (int j = 0; j < 2; ++j)                               \
                        acc[i][j] = __builtin_amdgcn_mfma_f32_16x16x32_f16(   \
                            af[i], bfv[j], acc[i][j], 0, 0, 0);               \
            }
            #define GROUP(t0, G)                                              \
            {                                                                 \
                WRITE_A(xq0, G ^ 1, 0) WRITE_A(xq1, G ^ 1, 1)                 \
                WRITE_A(xq2, G ^ 1, 2) WRITE_A(xq3, G ^ 1, 3)                 \
                xq0 = LOADX((t0) + 8);  xq1 = LOADX((t0) + 9);                \
                xq2 = LOADX((t0) + 10); xq3 = LOADX((t0) + 11);               \
                COMPUTE(G, 0, bfA) LOADB((t0) + 2, bfA)                       \
                COMPUTE(G, 1, bfB) LOADB((t0) + 3, bfB)                       \
                COMPUTE(G, 2, bfA) LOADB((t0) + 4, bfA)                       \
                COMPUTE(G, 3, bfB) LOADB((t0) + 5, bfB)                       \
                lds_barrier();                                                \
            }

            f32x4 acc[4][2] = {};
            f16x8 bfA[2], bfB[2];
            float4 xq0, xq1, xq2, xq3;

            // prologue: stage group 0, preload x for group 1, B(kb),B(kb+1)
            xq0 = LOADX(kb + 0); xq1 = LOADX(kb + 1);
            xq2 = LOADX(kb + 2); xq3 = LOADX(kb + 3);
            WRITE_A(xq0, 0, 0) WRITE_A(xq1, 0, 1)
            WRITE_A(xq2, 0, 2) WRITE_A(xq3, 0, 3)
            xq0 = LOADX(kb + 4); xq1 = LOADX(kb + 5);
            xq2 = LOADX(kb + 6); xq3 = LOADX(kb + 7);
            LOADB(kb, bfA) LOADB(kb + 1, bfB)
            lds_barrier();

            // 14 steady groups (t0 = kb .. kb+52); x issue reaches kb+63 max
            for (int gg = 0; gg < 14; gg += 2) {
                const int t0 = kb + gg * 4;
                GROUP(t0, 0)
                GROUP(t0 + 4, 1)
            }
            // group 14 (t0 = kb+56, G=0): stage group 15, no x issue
            {
                WRITE_A(xq0, 1, 0) WRITE_A(xq1, 1, 1)
                WRITE_A(xq2, 1, 2) WRITE_A(xq3, 1, 3)
                COMPUTE(0, 0, bfA) LOADB(kb + 58, bfA)
                COMPUTE(0, 1, bfB) LOADB(kb + 59, bfB)
                COMPUTE(0, 2, bfA) LOADB(kb + 60, bfA)
                COMPUTE(0, 3, bfB) LOADB(kb + 61, bfB)
                lds_barrier();
            }
            // group 15 (t0 = kb+60, G=1): final
            {
                COMPUTE(1, 0, bfA) LOADB(kb + 62, bfA)
                COMPUTE(1, 1, bfB) LOADB(kb + 63, bfB)
                COMPUTE(1, 2, bfA)
                COMPUTE(1, 3, bfB)
            }
            #undef LOADB
            #undef LOADX
            #undef WRITE_A
            #undef COMPUTE
            #undef GROUP

            // store partial: kh=0 -> zA (no bias); kh=1 -> zB (+bias)
            float* zt = kh ? zB : zA;
            #pragma unroll
            for (int j = 0; j < 2; ++j) {
                const int nn = n0 + w * 32 + j * 16 + fr;
                const float bj = kh ? bias[nn] : 0.0f;
                #pragma unroll
                for (int i = 0; i < 4; ++i)
                    #pragma unroll
                    for (int rr = 0; rr < 4; ++rr)
                        zt[(size_t)(m0 + i * 16 + q * 4 + rr) * G4H + nn]
                            = acc[i][j][rr] + bj;
            }

            // publish: fence all stores, then one release-add per item
            __threadfence();
            __syncthreads();
            if (tid == 0)
                __hip_atomic_fetch_add(&flags[(b << 2) + s], 1u,
                                       __ATOMIC_RELEASE, __HIP_MEMORY_SCOPE_AGENT);
            __syncthreads();
        }
    } else {
        // ------------------------- LSTM consumer -------------------------
        // Waves 0..7 (tid<512) run R23's proven step; waves 8..15 hit only
        // the barriers (shared control flow -> counts trivially match).
        const int b    = bid;
        const int lt   = tid;              // used below only when tid<512
        const int w    = (lt >> 6) & 7;
        const int lane = lt & 63;
        const int l15  = lane & 15;
        const int q    = lane >> 4;
        const int jj   = w * 16 + l15;

        _Float16 (*hA)[128] = reinterpret_cast<_Float16(*)[128]>(smem);

        f16x8 bf[4][4];
        float cstate = 0.f;
        const float* zqA = zA + (size_t)b * T_ * G4H + jj;
        const float* zqB = zB + (size_t)b * T_ * G4H + jj;
        float*     hbase = hs + (size_t)b * T_ * H_;
        const f32x4 zero4 = {0.f, 0.f, 0.f, 0.f};

        if (tid < 512) {
            #pragma unroll
            for (int g = 0; g < 4; ++g)
                #pragma unroll
                for (int kf = 0; kf < 4; ++kf)
                    bf[g][kf] = *reinterpret_cast<const f16x8*>(
                        &wrT[(size_t)(g * H_ + jj) * H_ + kf * 32 + q * 8]);
            if (tid < 128) reinterpret_cast<unsigned int*>(hA)[tid] = 0u;
        }

        if (tid == 0) wait4(&flags[b << 2]);   // slice 0 ready
        __syncthreads();

        #define LOADZ(t, d)                                                   \
        {                                                                     \
            int zo = (((t) & (T_ - 1)) << 9);                                 \
            d.x = zqA[zo]       + zqB[zo];                                    \
            d.y = zqA[zo + 128] + zqB[zo + 128];                              \
            d.z = zqA[zo + 256] + zqB[zo + 256];                              \
            d.w = zqA[zo + 384] + zqB[zo + 384];                              \
        }

        float4 zP0, zP1, zP2, zP3;
        if (tid < 512) {
            LOADZ(0, zP0) LOADZ(1, zP1) LOADZ(2, zP2) LOADZ(3, zP3)
        }
        __syncthreads();

        #define FSTEP(t, CUR, ZZ)                                             \
        {                                                                     \
            if (tid < 512) {                                                  \
                f16x8 af0 = *reinterpret_cast<const f16x8*>(&hA[CUR][0 * 32 + q * 8]); \
                f16x8 af1 = *reinterpret_cast<const f16x8*>(&hA[CUR][1 * 32 + q * 8]); \
                f16x8 af2 = *reinterpret_cast<const f16x8*>(&hA[CUR][2 * 32 + q * 8]); \
                f16x8 af3 = *reinterpret_cast<const f16x8*>(&hA[CUR][3 * 32 + q * 8]); \
                float zt0_ = ZZ.x, zt1_ = ZZ.y, zt2_ = ZZ.z, zt3_ = ZZ.w;     \
                LOADZ((t) + 4, ZZ)                                            \
                float gv[4];                                                  \
                _Pragma("unroll")                                             \
                for (int g = 0; g < 4; ++g) {                                 \
                    f32x4 aA = __builtin_amdgcn_mfma_f32_16x16x32_f16(        \
                        af0, bf[g][0], zero4, 0, 0, 0);                       \
                    aA = __builtin_amdgcn_mfma_f32_16x16x32_f16(              \
                        af1, bf[g][1], aA, 0, 0, 0);                          \
                    f32x4 aB = __builtin_amdgcn_mfma_f32_16x16x32_f16(        \
                        af2, bf[g][2], zero4, 0, 0, 0);                       \
                    aB = __builtin_amdgcn_mfma_f32_16x16x32_f16(              \
                        af3, bf[g][3], aB, 0, 0, 0);                          \
                    gv[g] = aA[0] + aB[0];                                    \
                }                                                             \
                float iv = sig_f(gv[0] + zt0_);                               \
                float fv = sig_f(gv[1] + zt1_);                               \
                float cc = tanh_f(gv[2] + zt2_);                              \
                float ov = sig_f(gv[3] + zt3_);                               \
                cstate = fv * cstate + iv * cc;                               \
                float h = ov * tanh_f(cstate);                                \
                if (q == 0) {                                                 \
                    hA[CUR ^ 1][jj] = (_Float16)h;                            \
                    hbase[((t) << 7) + jj] = h;                               \
                }                                                             \
            }                                                                 \
            lds_barrier();                                                    \
        }

        for (int s8 = 0; s8 < 4; ++s8) {
            const int tb = s8 * 128;
            for (int tq = 0; tq < 124; tq += 4) {
                FSTEP(tb + tq + 0, 0, zP0)
                FSTEP(tb + tq + 1, 1, zP1)
                FSTEP(tb + tq + 2, 0, zP2)
                FSTEP(tb + tq + 3, 1, zP3)
            }
            // last 4 steps prefetch slice s8+1 -> wait its flag first
            if (s8 < 3) {
                if (tid == 0) wait4(&flags[(b << 2) + s8 + 1]);
                __syncthreads();
            }
            FSTEP(tb + 124, 0, zP0)
            FSTEP(tb + 125, 1, zP1)
            FSTEP(tb + 126, 0, zP2)
            FSTEP(tb + 127, 1, zP3)
        }
        #undef FSTEP
        #undef LOADZ
    }

    // consume pads (keeps them live the whole kernel -> vgpr_count > 64)
    asm volatile("" ::
        "v"(pv[0]),  "v"(pv[1]),  "v"(pv[2]),  "v"(pv[3]),
        "v"(pv[4]),  "v"(pv[5]),  "v"(pv[6]),  "v"(pv[7]),
        "v"(pv[8]),  "v"(pv[9]),  "v"(pv[10]), "v"(pv[11]),
        "v"(pv[12]), "v"(pv[13]), "v"(pv[14]), "v"(pv[15]),
        "v"(pv[16]), "v"(pv[17]), "v"(pv[18]), "v"(pv[19]),
        "v"(pv[20]), "v"(pv[21]), "v"(pv[22]), "v"(pv[23]),
        "v"(pv[24]), "v"(pv[25]), "v"(pv[26]), "v"(pv[27]),
        "v"(pv[28]), "v"(pv[29]), "v"(pv[30]), "v"(pv[31]));
}

// ===========================================================================
// SERIAL FALLBACK PATH: exact R23 kernels (total 357.5us known-good).
// ===========================================================================
__global__ __launch_bounds__(512, 4) void gemm_fused(
    const float* __restrict__ x, const _Float16* __restrict__ btK,
    const float* __restrict__ bias, float* __restrict__ z)
{
    __shared__ __align__(16) _Float16 As[2][4][64 * 32];   // 32 KB

    const int tid = threadIdx.x;
    const int w   = tid >> 6;
    const int l   = tid & 63;
    const int fr  = l & 15;
    const int q   = l >> 4;

    const int bid   = blockIdx.x;
    const int xcd   = bid & 7;
    const int idx   = bid >> 3;
    const int mt    = xcd * 32 + (idx >> 1);
    const int ntile = idx & 1;
    const int m0    = mt * 64;
    const int n0    = ntile * 256;

    const int ar = tid >> 3;
    const int hc = (tid & 7) * 4;
    const int abyte = ((((hc >> 3) ^ ((ar >> 1) & 3)) << 4) | ((hc << 1) & 15));
    const float* xrow = x + (size_t)(m0 + ar) * F_ + hc;

    const int nA = n0 + w * 32 + fr;
    const int nB = nA + 16;
    const _Float16* bp0 = btK + (size_t)nA * 32 + ((q ^ ((nA >> 1) & 3)) << 3);
    const _Float16* bp1 = btK + (size_t)nB * 32 + ((q ^ ((nB >> 1) & 3)) << 3);

    #define LOADB(t, bfv)                                                     \
    {                                                                         \
        bfv[0] = *reinterpret_cast<const f16x8*>(bp0 + (size_t)(t) * 16384);  \
        bfv[1] = *reinterpret_cast<const f16x8*>(bp1 + (size_t)(t) * 16384);  \
    }
    #define LOADX(t) (*reinterpret_cast<const float4*>(xrow + (size_t)(t) * 32))
    #define WRITE_A(v, G, s)                                                  \
    {                                                                         \
        f16x4 hh; hh[0] = (_Float16)v.x; hh[1] = (_Float16)v.y;               \
        hh[2] = (_Float16)v.z; hh[3] = (_Float16)v.w;                         \
        *reinterpret_cast<f16x4*>(                                            \
            reinterpret_cast<char*>(&As[G][s][0]) + ar * 64 + abyte) = hh;    \
    }
    #define COMPUTE(G, s, bfv)                                                \
    {                                                                         \
        f16x8 af[4];                                                          \
        _Pragma("unroll")                                                     \
        for (int i = 0; i < 4; ++i) {                                         \
            int r   = i * 16 + fr;                                            \
            int off = r * 64 + ((q ^ ((r >> 1) & 3)) << 4);                   \
            af[i] = *reinterpret_cast<const f16x8*>(                          \
                reinterpret_cast<const char*>(&As[G][s][0]) + off);           \
        }                                                                     \
        _Pragma("unroll")                                                     \
        for (int i = 0; i < 4; ++i)                                           \
            _Pragma("unroll")                                                 \
            for (int j = 0; j < 2; ++j)                                       \
                acc[i][j] = __builtin_amdgcn_mfma_f32_16x16x32_f16(           \
                    af[i], bfv[j], acc[i][j], 0, 0, 0);                       \
    }
    #define GROUP(t0, G)                                                      \
    {                                                                         \
        WRITE_A(xq0, G ^ 1, 0) WRITE_A(xq1, G ^ 1, 1)                         \
        WRITE_A(xq2, G ^ 1, 2) WRITE_A(xq3, G ^ 1, 3)                         \
        xq0 = LOADX((t0) + 8);  xq1 = LOADX((t0) + 9);                        \
        xq2 = LOADX((t0) + 10); xq3 = LOADX((t0) + 11);                       \
        COMPUTE(G, 0, bfA) LOADB((t0) + 2, bfA)                               \
        COMPUTE(G, 1, bfB) LOADB((t0) + 3, bfB)                               \
        COMPUTE(G, 2, bfA) LOADB((t0) + 4, bfA)                               \
        COMPUTE(G, 3, bfB) LOADB((t0) + 5, bfB)                               \
        lds_barrier();                                                        \
    }

    f32x4 acc[4][2] = {};
    f16x8 bfA[2], bfB[2];
    float4 xq0, xq1, xq2, xq3;

    xq0 = LOADX(0); xq1 = LOADX(1); xq2 = LOADX(2); xq3 = LOADX(3);
    WRITE_A(xq0, 0, 0) WRITE_A(xq1, 0, 1) WRITE_A(xq2, 0, 2) WRITE_A(xq3, 0, 3)
    xq0 = LOADX(4); xq1 = LOADX(5); xq2 = LOADX(6); xq3 = LOADX(7);
    LOADB(0, bfA) LOADB(1, bfB)
    lds_barrier();

    for (int gg = 0; gg < 30; gg += 2) {
        const int t0 = gg * 4;
        GROUP(t0, 0)
        GROUP(t0 + 4, 1)
    }
    {
        WRITE_A(xq0, 1, 0) WRITE_A(xq1, 1, 1) WRITE_A(xq2, 1, 2) WRITE_A(xq3, 1, 3)
        COMPUTE(0, 0, bfA) LOADB(122, bfA)
        COMPUTE(0, 1, bfB) LOADB(123, bfB)
        COMPUTE(0, 2, bfA) LOADB(124, bfA)
        COMPUTE(0, 3, bfB) LOADB(125, bfB)
        lds_barrier();
    }
    {
        COMPUTE(1, 0, bfA) LOADB(126, bfA)
        COMPUTE(1, 1, bfB) LOADB(127, bfB)
        COMPUTE(1, 2, bfA)
        COMPUTE(1, 3, bfB)
    }
    #undef LOADB
    #undef LOADX
    #undef WRITE_A
    #undef COMPUTE
    #undef GROUP

    #pragma unroll
    for (int j = 0; j < 2; ++j) {
        const int nn = n0 + w * 32 + j * 16 + fr;
        const float bj = bias[nn];
        #pragma unroll
        for (int i = 0; i < 4; ++i)
            #pragma unroll
            for (int r = 0; r < 4; ++r)
                z[(size_t)(m0 + i * 16 + q * 4 + r) * G4H + nn]
                    = acc[i][j][r] + bj;
    }
}

__global__ __launch_bounds__(512, 2) void lstm_mfma(
    const float* __restrict__ z, const _Float16* __restrict__ wrT,
    float* __restrict__ hs, float* __restrict__ cst,
    _Float16* __restrict__ h16, int t0)
{
    const int b    = blockIdx.x;
    const int tid  = threadIdx.x;
    const int w    = tid >> 6;
    const int lane = tid & 63;
    const int l15  = lane & 15;
    const int q    = lane >> 4;
    const int jj   = w * 16 + l15;

    __shared__ __align__(16) _Float16 hA[2][128];

    f16x8 bf[4][4];
    #pragma unroll
    for (int g = 0; g < 4; ++g)
        #pragma unroll
        for (int kf = 0; kf < 4; ++kf)
            bf[g][kf] = *reinterpret_cast<const f16x8*>(
                &wrT[(size_t)(g * H_ + jj) * H_ + kf * 32 + q * 8]);

    float cstate;
    if (t0 == 0) {
        if (tid < 128) reinterpret_cast<unsigned int*>(hA)[tid] = 0u;
        cstate = 0.f;
    } else {
        if (tid < 64)
            reinterpret_cast<unsigned int*>(hA[0])[tid] =
                reinterpret_cast<const unsigned int*>(h16 + (size_t)b * H_)[tid];
        cstate = cst[(size_t)b * H_ + jj];
    }

    const float* zq    = z  + (size_t)b * T_ * G4H + jj;
    float*       hbase = hs + (size_t)b * T_ * H_;
    const f32x4 zero4 = {0.f, 0.f, 0.f, 0.f};

    #define LOADZ(t, d)                                                       \
    {                                                                         \
        int zo = (((t) & (T_ - 1)) << 9);                                     \
        d.x = zq[zo];       d.y = zq[zo + 128];                               \
        d.z = zq[zo + 256]; d.w = zq[zo + 384];                               \
    }

    float4 zP0, zP1, zP2, zP3;
    LOADZ(t0 + 0, zP0) LOADZ(t0 + 1, zP1)
    LOADZ(t0 + 2, zP2) LOADZ(t0 + 3, zP3)

    __syncthreads();

    #define LSTM_STEP(t, CUR, ZZ)                                             \
    {                                                                         \
        f16x8 af0 = *reinterpret_cast<const f16x8*>(&hA[CUR][0 * 32 + q * 8]);\
        f16x8 af1 = *reinterpret_cast<const f16x8*>(&hA[CUR][1 * 32 + q * 8]);\
        f16x8 af2 = *reinterpret_cast<const f16x8*>(&hA[CUR][2 * 32 + q * 8]);\
        f16x8 af3 = *reinterpret_cast<const f16x8*>(&hA[CUR][3 * 32 + q * 8]);\
        float zt0_ = ZZ.x, zt1_ = ZZ.y, zt2_ = ZZ.z, zt3_ = ZZ.w;             \
        LOADZ((t) + 4, ZZ)                                                    \
        float gv[4];                                                          \
        _Pragma("unroll")                                                     \
        for (int g = 0; g < 4; ++g) {                                         \
            f32x4 aA = __builtin_amdgcn_mfma_f32_16x16x32_f16(                \
                af0, bf[g][0], zero4, 0, 0, 0);                               \
            aA = __builtin_amdgcn_mfma_f32_16x16x32_f16(                      \
                af1, bf[g][1], aA, 0, 0, 0);                                  \
            f32x4 aB = __builtin_amdgcn_mfma_f32_16x16x32_f16(                \
                af2, bf[g][2], zero4, 0, 0, 0);                               \
            aB = __builtin_amdgcn_mfma_f32_16x16x32_f16(                      \
                af3, bf[g][3], aB, 0, 0, 0);                                  \
            gv[g] = aA[0] + aB[0];                                            \
        }                                                                     \
        float iv = sig_f(gv[0] + zt0_);                                       \
        float fv = sig_f(gv[1] + zt1_);                                       \
        float cc = tanh_f(gv[2] + zt2_);                                      \
        float ov = sig_f(gv[3] + zt3_);                                       \
        cstate = fv * cstate + iv * cc;                                       \
        float h = ov * tanh_f(cstate);                                        \
        if (q == 0) {                                                         \
            hA[CUR ^ 1][jj] = (_Float16)h;                                    \
            hbase[((t) << 7) + jj] = h;                                       \
        }                                                                     \
        lds_barrier();                                                        \
    }

    for (int t = t0; t < t0 + 256; t += 4) {
        LSTM_STEP(t,     0, zP0)
        LSTM_STEP(t + 1, 1, zP1)
        LSTM_STEP(t + 2, 0, zP2)
        LSTM_STEP(t + 3, 1, zP3)
    }
    #undef LSTM_STEP
    #undef LOADZ

    if (q == 0) cst[(size_t)b * H_ + jj] = cstate;
    if (tid < 64)
        reinterpret_cast<unsigned int*>(h16 + (size_t)b * H_)[tid] =
            reinterpret_cast<unsigned int*>(hA[0])[tid];
}

// ---------------------------------------------------------------------------
// Kernel 3: out = hs @ Wd + bd
// ---------------------------------------------------------------------------
__global__ __launch_bounds__(256) void dense_out(
    const float* __restrict__ hs, const float* __restrict__ Wd,
    const float* __restrict__ bd, float* __restrict__ out)
{
    int idx = blockIdx.x * 256 + threadIdx.x;
    if (idx >= B_ * T_ * NCLS) return;
    int cls = idx % NCLS;
    int row = idx / NCLS;
    const float* h = hs + (size_t)row * H_;
    float acc = bd[cls];
    #pragma unroll 8
    for (int k = 0; k < H_; ++k) acc += h[k] * Wd[k * NCLS + cls];
    out[idx] = acc;
}

// ---------------------------------------------------------------------------
extern "C" void kernel_launch(void* const* d_in, const int* in_sizes, int n_in,
                              void* d_out, int out_size, void* d_ws, size_t ws_size,
                              hipStream_t stream)
{
    const float* x  = (const float*)d_in[0];
    const float* Wk = (const float*)d_in[1];
    const float* Wr = (const float*)d_in[2];
    const float* b  = (const float*)d_in[3];
    const float* Wd = (const float*)d_in[4];
    const float* bd = (const float*)d_in[5];
    float* out = (float*)d_out;

    const size_t zElems  = (size_t)M_ * G4H;       // 8 Mi floats
    const size_t hsElems = (size_t)M_ * H_;
    const size_t need_ov = (2 * zElems + hsElems) * 4 +
                           (size_t)G4H * F_ * 2 + (size_t)G4H * H_ * 2 +
                           128 * 4 + 256;

    if (ws_size >= need_ov) {
        // ---------------- overlap path ----------------
        float*        zA    = (float*)d_ws;
        float*        zB    = zA + zElems;
        float*        hs    = zB + zElems;
        _Float16*     btK   = (_Float16*)(hs + hsElems);
        _Float16*     wrT   = btK + (size_t)G4H * F_;
        unsigned int* flags = (unsigned int*)(wrT + (size_t)G4H * H_);

        cvt_wkT<<<dim3(F_ / 64, G4H / 64), 256, 0, stream>>>(Wk, btK);
        cvt_wrT<<<dim3(H_ / 64, G4H / 64), 256, 0, stream>>>(Wr, wrT, flags);
        fused_overlap<<<256, 1024, 0, stream>>>(x, btK, b, zA, zB, wrT, hs, flags);
        int total = B_ * T_ * NCLS;
        dense_out<<<(total + 255) / 256, 256, 0, stream>>>(hs, Wd, bd, out);
    } else {
        // ---------------- serial fallback (exact R23) ----------------
        float*        z     = (float*)d_ws;
        float*        hs    = z + zElems;
        _Float16*     btK   = (_Float16*)(hs + hsElems);
        _Float16*     wrT   = btK + (size_t)G4H * F_;
        float*        cst   = (float*)(wrT + (size_t)G4H * H_);
        _Float16*     h16   = (_Float16*)(cst + (size_t)B_ * H_);
        unsigned int* flags = (unsigned int*)(h16 + (size_t)B_ * H_);

        cvt_wkT<<<dim3(F_ / 64, G4H / 64), 256, 0, stream>>>(Wk, btK);
        cvt_wrT<<<dim3(H_ / 64, G4H / 64), 256, 0, stream>>>(Wr, wrT, flags);
        gemm_fused<<<512, 512, 0, stream>>>(x, btK, b, z);
        lstm_mfma<<<B_, 512, 0, stream>>>(z, wrT, hs, cst, h16, 0);
        lstm_mfma<<<B_, 512, 0, stream>>>(z, wrT, hs, cst, h16, 256);
        int total = B_ * T_ * NCLS;
        dense_out<<<(total + 255) / 256, 256, 0, stream>>>(hs, Wd, bd, out);
    }
}

// Round 12
// 350.639 us; speedup vs baseline: 2.4067x; 2.4067x over previous
//
#include <hip/hip_runtime.h>
#include <hip/hip_bf16.h>
#include <hip/hip_fp16.h>
#include <math.h>

// Problem dims (fixed by reference)
#define B_  32
#define T_  512
#define F_  4096
#define H_  128
#define G4H 512           // 4*H
#define NCLS 3            // NUM_CLASSES + 1
#define M_  (B_ * T_)     // 16384 rows
#define KSTEPS 128        // F_/32

typedef _Float16 f16x8 __attribute__((ext_vector_type(8)));
typedef _Float16 f16x4 __attribute__((ext_vector_type(4)));
typedef float    f32x4 __attribute__((ext_vector_type(4)));

// ---------------------------------------------------------------------------
// Kernel 0b: Wk [F,4H] fp32 -> btK fp16, K-MAJOR tiles with baked-in group
// swizzle: group g (8 halves) of column n stored at half-offset
//   n*32 + ((g ^ ((n>>1)&3)) << 3)
// ---------------------------------------------------------------------------
__global__ __launch_bounds__(256) void cvt_wkT(
    const float* __restrict__ Wk, _Float16* __restrict__ btK)
{
    __shared__ float ls[64][65];
    const int k0 = blockIdx.x * 64;
    const int n0 = blockIdx.y * 64;
    const int tid = threadIdx.x;

    {
        int r  = tid >> 4;
        int c4 = (tid & 15) * 4;
        #pragma unroll
        for (int p = 0; p < 4; ++p) {
            float4 v = *reinterpret_cast<const float4*>(
                &Wk[(size_t)(k0 + r + p * 16) * G4H + n0 + c4]);
            ls[r + p * 16][c4 + 0] = v.x;
            ls[r + p * 16][c4 + 1] = v.y;
            ls[r + p * 16][c4 + 2] = v.z;
            ls[r + p * 16][c4 + 3] = v.w;
        }
    }
    __syncthreads();
    {
        int rn = tid >> 2;            // n within tile 0..63
        int ck = (tid & 3) * 16;      // k within tile 0,16,32,48
        f16x8 h0, h1;
        #pragma unroll
        for (int j = 0; j < 8; ++j) {
            h0[j] = (_Float16)ls[ck + j][rn];
            h1[j] = (_Float16)ls[ck + 8 + j][rn];
        }
        const int n    = n0 + rn;
        const int kg   = k0 + ck;
        const int kblk = kg >> 5;
        const int kk   = kg & 31;           // 0 or 16
        const int g0   = kk >> 3;           // 0 or 2
        const int sw   = (n >> 1) & 3;
        _Float16* base = btK + (size_t)kblk * (512 * 32) + (size_t)n * 32;
        *reinterpret_cast<f16x8*>(base + ((g0 ^ sw) << 3))       = h0;
        *reinterpret_cast<f16x8*>(base + (((g0 + 1) ^ sw) << 3)) = h1;
    }
}

// ---------------------------------------------------------------------------
// Kernel 0c: Wr [H,4H] fp32 -> wrT [4H,H] fp16 (transpose). grid (2, 8).
// ---------------------------------------------------------------------------
__global__ __launch_bounds__(256) void cvt_wrT(
    const float* __restrict__ Wr, _Float16* __restrict__ wrT)
{
    __shared__ float ls[64][65];
    const int k0 = blockIdx.x * 64;
    const int n0 = blockIdx.y * 64;
    const int tid = threadIdx.x;
    {
        int r  = tid >> 4;
        int c4 = (tid & 15) * 4;
        #pragma unroll
        for (int p = 0; p < 4; ++p) {
            float4 v = *reinterpret_cast<const float4*>(
                &Wr[(size_t)(k0 + r + p * 16) * G4H + n0 + c4]);
            ls[r + p * 16][c4 + 0] = v.x;
            ls[r + p * 16][c4 + 1] = v.y;
            ls[r + p * 16][c4 + 2] = v.z;
            ls[r + p * 16][c4 + 3] = v.w;
        }
    }
    __syncthreads();
    {
        int rn = tid >> 2;
        int ck = (tid & 3) * 16;
        f16x8 h0, h1;
        #pragma unroll
        for (int j = 0; j < 8; ++j) {
            h0[j] = (_Float16)ls[ck + j][rn];
            h1[j] = (_Float16)ls[ck + 8 + j][rn];
        }
        _Float16* dst = &wrT[(size_t)(n0 + rn) * H_ + k0 + ck];
        *reinterpret_cast<f16x8*>(dst)     = h0;
        *reinterpret_cast<f16x8*>(dst + 8) = h1;
    }
}

// Light producer-consumer barrier: LDS-drain only, no vmcnt drain.
__device__ __forceinline__ void lds_barrier() {
    asm volatile("s_waitcnt lgkmcnt(0)" ::: "memory");
    __builtin_amdgcn_s_barrier();
    asm volatile("" ::: "memory");
}

// ---------------------------------------------------------------------------
// Kernel 1: FUSED z = f16(x) @ Wk + b.  == R23 SOURCE VERBATIM ==
// (best measured config, total 357.5us). B in regs 2-deep, 4-step barrier
// groups, planar z store [row][gate*128+ch].
// ---------------------------------------------------------------------------
__global__ __launch_bounds__(512, 4) void gemm_fused(
    const float* __restrict__ x, const _Float16* __restrict__ btK,
    const float* __restrict__ bias, float* __restrict__ z)
{
    __shared__ __align__(16) _Float16 As[2][4][64 * 32];   // 32 KB

    const int tid = threadIdx.x;
    const int w   = tid >> 6;
    const int l   = tid & 63;
    const int fr  = l & 15;
    const int q   = l >> 4;

    // 512 blocks = 8 xcd * (32 m-pairs * 2 n); siblings adjacent on one XCD
    const int bid   = blockIdx.x;
    const int xcd   = bid & 7;
    const int idx   = bid >> 3;
    const int mt    = xcd * 32 + (idx >> 1);
    const int ntile = idx & 1;
    const int m0    = mt * 64;
    const int n0    = ntile * 256;

    // x staging: thread -> (row ar, cols hc..hc+3), swizzled f16 LDS layout
    const int ar = tid >> 3;
    const int hc = (tid & 7) * 4;
    const int abyte = ((((hc >> 3) ^ ((ar >> 1) & 3)) << 4) | ((hc << 1) & 15));
    const float* xrow = x + (size_t)(m0 + ar) * F_ + hc;

    // per-lane B pointers (swizzle baked into btK storage)
    const int nA = n0 + w * 32 + fr;        // j = 0 column
    const int nB = nA + 16;                 // j = 1 column
    const _Float16* bp0 = btK + (size_t)nA * 32 + ((q ^ ((nA >> 1) & 3)) << 3);
    const _Float16* bp1 = btK + (size_t)nB * 32 + ((q ^ ((nB >> 1) & 3)) << 3);

    #define LOADB(t, bfv)                                                     \
    {                                                                         \
        bfv[0] = *reinterpret_cast<const f16x8*>(bp0 + (size_t)(t) * 16384);  \
        bfv[1] = *reinterpret_cast<const f16x8*>(bp1 + (size_t)(t) * 16384);  \
    }

    #define LOADX(t) (*reinterpret_cast<const float4*>(xrow + (size_t)(t) * 32))

    #define WRITE_A(v, G, s)                                                  \
    {                                                                         \
        f16x4 hh; hh[0] = (_Float16)v.x; hh[1] = (_Float16)v.y;               \
        hh[2] = (_Float16)v.z; hh[3] = (_Float16)v.w;                         \
        *reinterpret_cast<f16x4*>(                                            \
            reinterpret_cast<char*>(&As[G][s][0]) + ar * 64 + abyte) = hh;    \
    }

    #define COMPUTE(G, s, bfv)                                                \
    {                                                                         \
        f16x8 af[4];                                                          \
        _Pragma("unroll")                                                     \
        for (int i = 0; i < 4; ++i) {                                         \
            int r   = i * 16 + fr;                                            \
            int off = r * 64 + ((q ^ ((r >> 1) & 3)) << 4);                   \
            af[i] = *reinterpret_cast<const f16x8*>(                          \
                reinterpret_cast<const char*>(&As[G][s][0]) + off);           \
        }                                                                     \
        _Pragma("unroll")                                                     \
        for (int i = 0; i < 4; ++i)                                           \
            _Pragma("unroll")                                                 \
            for (int j = 0; j < 2; ++j)                                       \
                acc[i][j] = __builtin_amdgcn_mfma_f32_16x16x32_f16(           \
                    af[i], bfv[j], acc[i][j], 0, 0, 0);                       \
    }

    // One group = 4 K-steps computed from As[G], staging group g+1 into
    // As[G^1], issuing x for group g+2. One barrier per group.
    #define GROUP(t0, G)                                                      \
    {                                                                         \
        WRITE_A(xq0, G ^ 1, 0) WRITE_A(xq1, G ^ 1, 1)                         \
        WRITE_A(xq2, G ^ 1, 2) WRITE_A(xq3, G ^ 1, 3)                         \
        xq0 = LOADX((t0) + 8);  xq1 = LOADX((t0) + 9);                        \
        xq2 = LOADX((t0) + 10); xq3 = LOADX((t0) + 11);                       \
        COMPUTE(G, 0, bfA) LOADB((t0) + 2, bfA)                               \
        COMPUTE(G, 1, bfB) LOADB((t0) + 3, bfB)                               \
        COMPUTE(G, 2, bfA) LOADB((t0) + 4, bfA)                               \
        COMPUTE(G, 3, bfB) LOADB((t0) + 5, bfB)                               \
        lds_barrier();                                                        \
    }

    f32x4 acc[4][2] = {};
    f16x8 bfA[2], bfB[2];
    float4 xq0, xq1, xq2, xq3;

    // prologue: stage group 0, preload x for group 1, B(0),B(1)
    xq0 = LOADX(0); xq1 = LOADX(1); xq2 = LOADX(2); xq3 = LOADX(3);
    WRITE_A(xq0, 0, 0) WRITE_A(xq1, 0, 1) WRITE_A(xq2, 0, 2) WRITE_A(xq3, 0, 3)
    xq0 = LOADX(4); xq1 = LOADX(5); xq2 = LOADX(6); xq3 = LOADX(7);
    LOADB(0, bfA) LOADB(1, bfB)
    lds_barrier();

    // groups 0..29 (t0 = 0..116): full steady state (x issue reaches t=127)
    for (int gg = 0; gg < 30; gg += 2) {
        const int t0 = gg * 4;
        GROUP(t0, 0)
        GROUP(t0 + 4, 1)
    }
    // group 30 (t0=120, G=0): stage group 31, no more x issue
    {
        WRITE_A(xq0, 1, 0) WRITE_A(xq1, 1, 1) WRITE_A(xq2, 1, 2) WRITE_A(xq3, 1, 3)
        COMPUTE(0, 0, bfA) LOADB(122, bfA)
        COMPUTE(0, 1, bfB) LOADB(123, bfB)
        COMPUTE(0, 2, bfA) LOADB(124, bfA)
        COMPUTE(0, 3, bfB) LOADB(125, bfB)
        lds_barrier();
    }
    // group 31 (t0=124, G=1): final
    {
        COMPUTE(1, 0, bfA) LOADB(126, bfA)
        COMPUTE(1, 1, bfB) LOADB(127, bfB)
        COMPUTE(1, 2, bfA)
        COMPUTE(1, 3, bfB)
    }

    #undef LOADB
    #undef LOADX
    #undef WRITE_A
    #undef COMPUTE
    #undef GROUP

    // planar z store: z[row][nn] (gate = nn>>7, ch = nn&127)
    #pragma unroll
    for (int j = 0; j < 2; ++j) {
        const int nn = n0 + w * 32 + j * 16 + fr;
        const float bj = bias[nn];
        #pragma unroll
        for (int i = 0; i < 4; ++i)
            #pragma unroll
            for (int r = 0; r < 4; ++r)
                z[(size_t)(m0 + i * 16 + q * 4 + r) * G4H + nn]
                    = acc[i][j][r] + bj;
    }
}

// ---------------------------------------------------------------------------
// Kernel 2: MFMA LSTM recurrence — R23's proven step body (planar z, raw
// v_exp/v_rcp gates, direct h store), MERGED back to one 512-step dispatch:
// the two-half split was a diagnostic; merging removes one launch, the
// cst/h16 global handoff, and a duplicate B-fragment prologue. Step code
// verbatim => bit-exact.
// ---------------------------------------------------------------------------
__device__ __forceinline__ float sig_f(float x) {
    return __builtin_amdgcn_rcpf(
        1.0f + __builtin_amdgcn_exp2f(-1.442695040888963f * x));
}
__device__ __forceinline__ float tanh_f(float x) {
    return 1.0f - 2.0f * __builtin_amdgcn_rcpf(
        1.0f + __builtin_amdgcn_exp2f(2.885390081777927f * x));
}

__global__ __launch_bounds__(512, 2) void lstm_mfma(
    const float* __restrict__ z,       // [B*T, 512] planar
    const _Float16* __restrict__ wrT,  // [4H, H] = Wr^T fp16
    float* __restrict__ hs)            // [B, T, H] fp32
{
    const int b    = blockIdx.x;
    const int tid  = threadIdx.x;
    const int w    = tid >> 6;
    const int lane = tid & 63;
    const int l15  = lane & 15;
    const int q    = lane >> 4;
    const int jj   = w * 16 + l15;

    __shared__ __align__(16) _Float16 hA[2][128];

    f16x8 bf[4][4];
    #pragma unroll
    for (int g = 0; g < 4; ++g)
        #pragma unroll
        for (int kf = 0; kf < 4; ++kf)
            bf[g][kf] = *reinterpret_cast<const f16x8*>(
                &wrT[(size_t)(g * H_ + jj) * H_ + kf * 32 + q * 8]);

    float cstate = 0.f;
    if (tid < 128) reinterpret_cast<unsigned int*>(hA)[tid] = 0u;

    const float* zq    = z  + (size_t)b * T_ * G4H + jj;   // + t*512 + g*128
    float*       hbase = hs + (size_t)b * T_ * H_;

    const f32x4 zero4 = {0.f, 0.f, 0.f, 0.f};

    #define LOADZ(t, d)                                                       \
    {                                                                         \
        int zo = (((t) & (T_ - 1)) << 9);                                     \
        d.x = zq[zo];       d.y = zq[zo + 128];                               \
        d.z = zq[zo + 256]; d.w = zq[zo + 384];                               \
    }

    float4 zP0, zP1, zP2, zP3;
    LOADZ(0, zP0) LOADZ(1, zP1) LOADZ(2, zP2) LOADZ(3, zP3)

    __syncthreads();

    #define LSTM_STEP(t, CUR, ZZ)                                             \
    {                                                                         \
        f16x8 af0 = *reinterpret_cast<const f16x8*>(&hA[CUR][0 * 32 + q * 8]);\
        f16x8 af1 = *reinterpret_cast<const f16x8*>(&hA[CUR][1 * 32 + q * 8]);\
        f16x8 af2 = *reinterpret_cast<const f16x8*>(&hA[CUR][2 * 32 + q * 8]);\
        f16x8 af3 = *reinterpret_cast<const f16x8*>(&hA[CUR][3 * 32 + q * 8]);\
        float zt0_ = ZZ.x, zt1_ = ZZ.y, zt2_ = ZZ.z, zt3_ = ZZ.w;             \
        LOADZ((t) + 4, ZZ)                                                    \
        float gv[4];                                                          \
        _Pragma("unroll")                                                     \
        for (int g = 0; g < 4; ++g) {                                         \
            f32x4 aA = __builtin_amdgcn_mfma_f32_16x16x32_f16(                \
                af0, bf[g][0], zero4, 0, 0, 0);                               \
            aA = __builtin_amdgcn_mfma_f32_16x16x32_f16(                      \
                af1, bf[g][1], aA, 0, 0, 0);                                  \
            f32x4 aB = __builtin_amdgcn_mfma_f32_16x16x32_f16(                \
                af2, bf[g][2], zero4, 0, 0, 0);                               \
            aB = __builtin_amdgcn_mfma_f32_16x16x32_f16(                      \
                af3, bf[g][3], aB, 0, 0, 0);                                  \
            gv[g] = aA[0] + aB[0];                                            \
        }                                                                     \
        float iv = sig_f(gv[0] + zt0_);                                       \
        float fv = sig_f(gv[1] + zt1_);                                       \
        float cc = tanh_f(gv[2] + zt2_);                                      \
        float ov = sig_f(gv[3] + zt3_);                                       \
        cstate = fv * cstate + iv * cc;                                       \
        float h = ov * tanh_f(cstate);                                        \
        if (q == 0) {                                                         \
            hA[CUR ^ 1][jj] = (_Float16)h;                                    \
            hbase[((t) << 7) + jj] = h;                                       \
        }                                                                     \
        lds_barrier();                                                        \
    }

    for (int t = 0; t < T_; t += 4) {
        LSTM_STEP(t,     0, zP0)
        LSTM_STEP(t + 1, 1, zP1)
        LSTM_STEP(t + 2, 0, zP2)
        LSTM_STEP(t + 3, 1, zP3)
    }
    #undef LSTM_STEP
    #undef LOADZ
}

// ---------------------------------------------------------------------------
// Kernel 3: out = hs @ Wd + bd
// ---------------------------------------------------------------------------
__global__ __launch_bounds__(256) void dense_out(
    const float* __restrict__ hs, const float* __restrict__ Wd,
    const float* __restrict__ bd, float* __restrict__ out)
{
    int idx = blockIdx.x * 256 + threadIdx.x;
    if (idx >= B_ * T_ * NCLS) return;
    int cls = idx % NCLS;
    int row = idx / NCLS;
    const float* h = hs + (size_t)row * H_;
    float acc = bd[cls];
    #pragma unroll 8
    for (int k = 0; k < H_; ++k) acc += h[k] * Wd[k * NCLS + cls];
    out[idx] = acc;
}

// ---------------------------------------------------------------------------
extern "C" void kernel_launch(void* const* d_in, const int* in_sizes, int n_in,
                              void* d_out, int out_size, void* d_ws, size_t ws_size,
                              hipStream_t stream)
{
    const float* x  = (const float*)d_in[0];
    const float* Wk = (const float*)d_in[1];
    const float* Wr = (const float*)d_in[2];
    const float* b  = (const float*)d_in[3];
    const float* Wd = (const float*)d_in[4];
    const float* bd = (const float*)d_in[5];
    float* out = (float*)d_out;

    float*     z   = (float*)d_ws;                       // [M, 512] fp32 planar
    float*     hs  = z + (size_t)M_ * G4H;               // [M, H]  fp32
    _Float16*  btK = (_Float16*)(hs + (size_t)M_ * H_);  // k-major swizzled, 4 MB
    _Float16*  wrT = btK + (size_t)G4H * F_;             // [4H, H] fp16

    cvt_wkT<<<dim3(F_ / 64, G4H / 64), 256, 0, stream>>>(Wk, btK);
    cvt_wrT<<<dim3(H_ / 64, G4H / 64), 256, 0, stream>>>(Wr, wrT);
    gemm_fused<<<512, 512, 0, stream>>>(x, btK, b, z);
    lstm_mfma<<<B_, 512, 0, stream>>>(z, wrT, hs);
    int total = B_ * T_ * NCLS;
    dense_out<<<(total + 255) / 256, 256, 0, stream>>>(hs, Wd, bd, out);
}